// Round 4
// baseline (552.651 us; speedup 1.0000x reference)
//
#include <hip/hip_runtime.h>
#include <hip/hip_bf16.h>
#include <stdint.h>

#define D 256
#define NBUCK 391            // ceil(100000 / 256) buckets of 256 nodes
#define BSHIFT 8
#define TILE 4096            // edges per block in binning pass

typedef short short8 __attribute__((ext_vector_type(8)));
typedef float f32x4 __attribute__((ext_vector_type(4)));

__device__ __forceinline__ float bf2f(unsigned short u) {
  return __uint_as_float(((unsigned)u) << 16);
}
__device__ __forceinline__ unsigned short f2bf(float f) {
  unsigned u = __float_as_uint(f);
  unsigned r = u + 0x7FFFu + ((u >> 16) & 1u);
  return (unsigned short)(r >> 16);
}

// ---------------- K1: coarse bucket histogram (LDS-binned) ----------------
__global__ void bucket_hist_kernel(const int* __restrict__ src, int* __restrict__ bcount, int E) {
  __shared__ int h[NBUCK];
  for (int i = threadIdx.x; i < NBUCK; i += 256) h[i] = 0;
  __syncthreads();
  int gid = blockIdx.x * 256 + threadIdx.x;
  for (int e = gid; e < E; e += 1024 * 256) atomicAdd(&h[src[e] >> BSHIFT], 1);
  __syncthreads();
  for (int i = threadIdx.x; i < NBUCK; i += 256) {
    int c = h[i];
    if (c) atomicAdd(&bcount[i], c);
  }
}

// ---------------- K2: exclusive scan of bucket counts ----------------
__global__ void bucket_scan_kernel(const int* __restrict__ bcount, int* __restrict__ bbase,
                                   int* __restrict__ gcursor) {
  __shared__ int sc[2][512];
  int tid = threadIdx.x;
  sc[0][tid] = (tid < NBUCK) ? bcount[tid] : 0;
  __syncthreads();
  int d = 0;
  for (int off = 1; off < 512; off <<= 1) {
    int v = sc[d][tid];
    if (tid >= off) v += sc[d][tid - off];
    sc[d ^ 1][tid] = v;
    __syncthreads();
    d ^= 1;
  }
  if (tid < NBUCK) {
    int excl = (tid == 0) ? 0 : sc[d][tid - 1];
    bbase[tid] = excl;
    gcursor[tid] = excl;
  }
}

// ---------------- K3: binning scatter ----------------
__launch_bounds__(256)
__global__ void binscatter_kernel(const int* __restrict__ src, const int* __restrict__ dst,
                                  int* __restrict__ gcursor, int* __restrict__ ebuf, int E) {
  __shared__ int hist[NBUCK];
  __shared__ int lstart[512];
  __shared__ int gbase[NBUCK];
  __shared__ int sc[2][512];
  __shared__ int stag[TILE];
  __shared__ unsigned short sbuck[TILE];

  int tid = threadIdx.x;
  int base = blockIdx.x * TILE;
  int tilecount = E - base;
  if (tilecount > TILE) tilecount = TILE;

  for (int i = tid; i < NBUCK; i += 256) hist[i] = 0;
  __syncthreads();

  int esrc[16], edst[16];
#pragma unroll
  for (int k = 0; k < 16; k++) {
    int e = base + k * 256 + tid;
    if (e < E) {
      esrc[k] = src[e];
      edst[k] = dst[e];
      atomicAdd(&hist[esrc[k] >> BSHIFT], 1);
    } else {
      esrc[k] = -1;
      edst[k] = 0;
    }
  }
  __syncthreads();

  for (int i = tid; i < 512; i += 256) sc[0][i] = (i < NBUCK) ? hist[i] : 0;
  __syncthreads();
  int d = 0;
  for (int off = 1; off < 512; off <<= 1) {
    for (int i = tid; i < 512; i += 256) {
      int v = sc[d][i];
      if (i >= off) v += sc[d][i - off];
      sc[d ^ 1][i] = v;
    }
    __syncthreads();
    d ^= 1;
  }
  for (int i = tid; i < 512; i += 256) lstart[i] = (i == 0) ? 0 : sc[d][i - 1];
  __syncthreads();

  for (int b = tid; b < NBUCK; b += 256) {
    int c = hist[b];
    if (c) gbase[b] = atomicAdd(&gcursor[b], c);
  }
  __syncthreads();

  for (int i = tid; i < NBUCK; i += 256) hist[i] = 0;
  __syncthreads();

#pragma unroll
  for (int k = 0; k < 16; k++) {
    if (esrc[k] >= 0) {
      int b = esrc[k] >> BSHIFT;
      int r = atomicAdd(&hist[b], 1);
      int pos = lstart[b] + r;
      stag[pos] = edst[k] | ((esrc[k] & 255) << 20);
      sbuck[pos] = (unsigned short)b;
    }
  }
  __syncthreads();

  for (int s = tid; s < tilecount; s += 256) {
    int b = sbuck[s];
    ebuf[gbase[b] + (s - lstart[b])] = stag[s];
  }
}

// ---------------- K4: per-bucket counting sort (1024 threads) ----------------
__launch_bounds__(1024)
__global__ void bucketsort_kernel(const int* __restrict__ ebuf, const int* __restrict__ bbase,
                                  const int* __restrict__ bcount, int* __restrict__ csr,
                                  int* __restrict__ offsets, int* __restrict__ ecount,
                                  float* __restrict__ rnorm, int N) {
  __shared__ int ncnt[256];
  __shared__ int nstart[256];
  __shared__ int sc[2][256];
  int tid = threadIdx.x;
  int b = blockIdx.x;
  int base = bbase[b];
  int cnt = bcount[b];
  int node0 = b << BSHIFT;

  if (tid < 256) ncnt[tid] = 0;
  __syncthreads();
  for (int s = tid; s < cnt; s += 1024) {
    int v = ebuf[base + s];
    atomicAdd(&ncnt[v >> 20], 1);
  }
  __syncthreads();

  int mycnt = (tid < 256) ? ncnt[tid] : 0;
  if (tid < 256) sc[0][tid] = mycnt;
  __syncthreads();
  int d = 0;
  for (int off = 1; off < 256; off <<= 1) {
    if (tid < 256) {
      int v = sc[d][tid];
      if (tid >= off) v += sc[d][tid - off];
      sc[d ^ 1][tid] = v;
    }
    __syncthreads();
    d ^= 1;
  }
  if (tid < 256) {
    nstart[tid] = (tid == 0) ? 0 : sc[d][tid - 1];
  }
  __syncthreads();

  int node = node0 + tid;
  if (tid < 256 && node < N) {
    offsets[node] = base + nstart[tid];
    ecount[node] = mycnt;
    rnorm[node] = rsqrtf((float)(mycnt + 1));
  }

  if (tid < 256) ncnt[tid] = 0;
  __syncthreads();
  for (int s = tid; s < cnt; s += 1024) {
    int v = ebuf[base + s];
    int nl = v >> 20;
    int r = atomicAdd(&ncnt[nl], 1);
    csr[base + nstart[nl] + r] = v & 0xFFFFF;
  }
}

// ---------------- fused GEMM: hs = rsqrt(deg) * (x @ W^T), fp32 in, bf16 out ----
// LDS chunked layout [k/8][row][8]: fragment ds_read_b128 is 16B-aligned and
// 2-way banked (free). B staged per 128-wide K-half (32 KB), A per 32-k step.
__launch_bounds__(256)
__global__ void gemm_kernel(const float* __restrict__ X,
                            const float* __restrict__ W,
                            unsigned short* __restrict__ Hout,
                            const float* __restrict__ rnorm, int n) {
  __shared__ unsigned short sB[16 * 128 * 8];   // 32 KB: [kchunk][col][8]
  __shared__ unsigned short sA[4 * 128 * 8];    // 8 KB:  [kchunk][row][8]
  int tid = threadIdx.x;
  int wave = tid >> 6, lane = tid & 63;
  int wm = wave >> 1, wn = wave & 1;
  int l16 = lane & 15, quad = lane >> 4;
  int arow0 = blockIdx.x * 128;
  int bcol0 = blockIdx.y * 128;

  f32x4 acc[4][4];
  const f32x4 zero = {0.f, 0.f, 0.f, 0.f};
#pragma unroll
  for (int i = 0; i < 4; i++)
#pragma unroll
    for (int j = 0; j < 4; j++) acc[i][j] = zero;

  for (int khalf = 0; khalf < 2; khalf++) {
    int kbase = khalf * 128;
    // stage B half: 128 cols x 128 k
#pragma unroll
    for (int it = 0; it < 16; ++it) {
      int i = it * 256 + tid;            // 0..4095 float4s
      int col = i >> 5;
      int kk = (i & 31) * 4;
      const float4 v = *(const float4*)&W[(bcol0 + col) * 256 + kbase + kk];
      ushort4 o;
      o.x = f2bf(v.x); o.y = f2bf(v.y); o.z = f2bf(v.z); o.w = f2bf(v.w);
      *(ushort4*)&sB[(kk >> 3) * 1024 + col * 8 + (kk & 7)] = o;
    }
    for (int k0 = kbase; k0 < kbase + 128; k0 += 32) {
      // stage A: 128 rows x 32 k
#pragma unroll
      for (int it = 0; it < 4; ++it) {
        int i = it * 256 + tid;          // 0..1023 float4s
        int row = i >> 3;
        int kk = (i & 7) * 4;
        int gr = arow0 + row;
        float4 v;
        if (gr < n) v = *(const float4*)&X[(size_t)gr * 256 + k0 + kk];
        else { v.x = v.y = v.z = v.w = 0.f; }
        ushort4 o;
        o.x = f2bf(v.x); o.y = f2bf(v.y); o.z = f2bf(v.z); o.w = f2bf(v.w);
        *(ushort4*)&sA[(kk >> 3) * 1024 + row * 8 + (kk & 7)] = o;
      }
      __syncthreads();
      int kc = (k0 - kbase) >> 3;        // base k-chunk in sB
      short8 af[4], bfr[4];
#pragma unroll
      for (int i = 0; i < 4; i++)
        af[i] = *(const short8*)&sA[quad * 1024 + (wm * 64 + i * 16 + l16) * 8];
#pragma unroll
      for (int j = 0; j < 4; j++)
        bfr[j] = *(const short8*)&sB[(kc + quad) * 1024 + (wn * 64 + j * 16 + l16) * 8];
#pragma unroll
      for (int i = 0; i < 4; i++)
#pragma unroll
        for (int j = 0; j < 4; j++)
          acc[i][j] = __builtin_amdgcn_mfma_f32_16x16x32_bf16(af[i], bfr[j], acc[i][j], 0, 0, 0);
      __syncthreads();
    }
  }

#pragma unroll
  for (int i = 0; i < 4; i++) {
    int rowb = arow0 + wm * 64 + i * 16 + quad * 4;
#pragma unroll
    for (int r = 0; r < 4; r++) {
      int gr = rowb + r;
      float rn = (gr < n) ? rnorm[gr] : 0.f;
#pragma unroll
      for (int j = 0; j < 4; j++) {
        int col = bcol0 + wn * 64 + j * 16 + l16;
        Hout[gr * 256 + col] = f2bf(acc[i][j][r] * rn);
      }
    }
  }
}

// ---------------- CSR gather, column-split + half-wave ----------------
// Pass covers cols [colbase, colbase+128). Half-wave h processes edges t+h;
// lane li owns 4 cols (8 B loads). Cross-half shfl_xor(32) reduce at end.
__launch_bounds__(256)
__global__ void gather_kernel(const unsigned short* __restrict__ hs,
                              const int* __restrict__ offsets,
                              const int* __restrict__ ecount,
                              const float* __restrict__ rnorm,
                              const int* __restrict__ csr,
                              float* __restrict__ out, int n, int colbase) {
  int wave = threadIdx.x >> 6, lane = threadIdx.x & 63;
  int h = lane >> 5, li = lane & 31;
  int node = blockIdx.x * 4 + wave;
  if (node >= n) return;
  int start = offsets[node], cnt = ecount[node];
  const unsigned short* hcol = hs + colbase + li * 4;
  float a0 = 0.f, a1 = 0.f, a2 = 0.f, a3 = 0.f;
  for (int base = 0; base < cnt; base += 64) {
    int m = cnt - base;
    if (m > 64) m = 64;
    int idxv = 0;
    if (lane < m) idxv = csr[start + base + lane];
    int t = 0;
    for (; t + 8 <= m; t += 8) {
      int e0 = __shfl(idxv, t + h);
      int e1 = __shfl(idxv, t + 2 + h);
      int e2 = __shfl(idxv, t + 4 + h);
      int e3 = __shfl(idxv, t + 6 + h);
      uint2 u0 = *(const uint2*)&hcol[e0 * 256];
      uint2 u1 = *(const uint2*)&hcol[e1 * 256];
      uint2 u2 = *(const uint2*)&hcol[e2 * 256];
      uint2 u3 = *(const uint2*)&hcol[e3 * 256];
      a0 += bf2f((unsigned short)u0.x) + bf2f((unsigned short)u1.x) +
            bf2f((unsigned short)u2.x) + bf2f((unsigned short)u3.x);
      a1 += bf2f((unsigned short)(u0.x >> 16)) + bf2f((unsigned short)(u1.x >> 16)) +
            bf2f((unsigned short)(u2.x >> 16)) + bf2f((unsigned short)(u3.x >> 16));
      a2 += bf2f((unsigned short)u0.y) + bf2f((unsigned short)u1.y) +
            bf2f((unsigned short)u2.y) + bf2f((unsigned short)u3.y);
      a3 += bf2f((unsigned short)(u0.y >> 16)) + bf2f((unsigned short)(u1.y >> 16)) +
            bf2f((unsigned short)(u2.y >> 16)) + bf2f((unsigned short)(u3.y >> 16));
    }
    for (; t < m; t += 2) {
      int dd = __shfl(idxv, t + h);
      if (t + h < m) {
        uint2 u = *(const uint2*)&hcol[dd * 256];
        a0 += bf2f((unsigned short)u.x);
        a1 += bf2f((unsigned short)(u.x >> 16));
        a2 += bf2f((unsigned short)u.y);
        a3 += bf2f((unsigned short)(u.y >> 16));
      }
    }
  }
  a0 += __shfl_xor(a0, 32);
  a1 += __shfl_xor(a1, 32);
  a2 += __shfl_xor(a2, 32);
  a3 += __shfl_xor(a3, 32);
  if (h == 0) {
    uint2 us = *(const uint2*)&hcol[node * 256];
    float rn = rnorm[node];
    float4 o;
    o.x = rn * (a0 + bf2f((unsigned short)us.x));
    o.y = rn * (a1 + bf2f((unsigned short)(us.x >> 16)));
    o.z = rn * (a2 + bf2f((unsigned short)us.y));
    o.w = rn * (a3 + bf2f((unsigned short)(us.y >> 16)));
    *(float4*)&out[node * 256 + colbase + li * 4] = o;
  }
}

extern "C" void kernel_launch(void* const* d_in, const int* in_sizes, int n_in,
                              void* d_out, int out_size, void* d_ws, size_t ws_size,
                              hipStream_t stream) {
  const float* x = (const float*)d_in[0];
  const float* W = (const float*)d_in[1];
  const int* ei = (const int*)d_in[2];
  float* out = (float*)d_out;

  int N = in_sizes[0] / D;        // 100000
  int E = in_sizes[2] / 2;        // 3200000
  int NPAD = (N + 127) & ~127;
  const int* src = ei;
  const int* dst = ei + E;

  char* p = (char*)d_ws;
  auto alloc = [&](size_t b) {
    char* r = p;
    p += (b + 255) & ~(size_t)255;
    return r;
  };
  unsigned short* hb = (unsigned short*)alloc((size_t)NPAD * D * 2);
  int* csr = (int*)alloc((size_t)E * 4);
  int* offsets = (int*)alloc((size_t)N * 4);
  int* ecount = (int*)alloc((size_t)N * 4);
  float* rnorm = (float*)alloc((size_t)N * 4);
  int* bcount = (int*)alloc(NBUCK * 4);
  int* bbase = (int*)alloc(NBUCK * 4);
  int* gcursor = (int*)alloc(NBUCK * 4);
  // ebuf (E*4 = 12.8 MB) aliases hb (51 MB): dead before gemm writes hb
  int* ebuf = (int*)hb;

  hipMemsetAsync(bcount, 0, NBUCK * 4, stream);
  bucket_hist_kernel<<<1024, 256, 0, stream>>>(src, bcount, E);
  bucket_scan_kernel<<<1, 512, 0, stream>>>(bcount, bbase, gcursor);
  binscatter_kernel<<<(E + TILE - 1) / TILE, 256, 0, stream>>>(src, dst, gcursor, ebuf, E);
  bucketsort_kernel<<<NBUCK, 1024, 0, stream>>>(ebuf, bbase, bcount, csr, offsets, ecount, rnorm, N);
  gemm_kernel<<<dim3(NPAD / 128, D / 128), 256, 0, stream>>>(x, W, hb, rnorm, N);
  gather_kernel<<<(N + 3) / 4, 256, 0, stream>>>(hb, offsets, ecount, rnorm, csr, out, N, 0);
  gather_kernel<<<(N + 3) / 4, 256, 0, stream>>>(hb, offsets, ecount, rnorm, csr, out, N, 128);
}